// Round 3
// baseline (1063.401 us; speedup 1.0000x reference)
//
#include <hip/hip_runtime.h>
#include <hip/hip_bf16.h>
#include <math.h>

// GAT: N=100000 nodes, E=1600000 edges (+N self loops), 3 layers.
// Inputs detected bf16 (runtime flag kept for safety). Intermediates bf16.

#define NNODES 100000
#define NEDGES 1600000
#define ENTOT  (NEDGES + NNODES)
#define NEG_SLOPE 0.2f
#define BN_EPS 1e-5f

typedef unsigned short u16;
typedef unsigned int u32;

__device__ __forceinline__ float b2f(u16 u){ union{u32 i; float f;} v; v.i=((u32)u)<<16; return v.f; }
__device__ __forceinline__ u16 f2b(float x){ __hip_bfloat16 b=__float2bfloat16(x); return *(u16*)&b; }
// external float tensor element i; f=1 -> fp32, f=0 -> bf16
__device__ __forceinline__ float ldf(const void* p, int i, int f){
  return f ? ((const float*)p)[i] : b2f(((const u16*)p)[i]);
}

// ---------------- dtype probe ----------------
__global__ void k_detect(const u16* __restrict__ x, int* __restrict__ flag){
  __shared__ int bad;
  if(threadIdx.x==0) bad=0;
  __syncthreads();
  int cnt=0;
  for(int i=threadIdx.x;i<4096;i+=256){
    u16 v = x[2*i];
    int ex = (v>>7)&0xff;
    if(ex==0xff || (ex==0 && (v&0x7fff)!=0)) cnt++;
  }
  atomicAdd(&bad,cnt);
  __syncthreads();
  if(threadIdx.x==0) flag[0] = (bad>4)?1:0;   // 1 = fp32, 0 = bf16
}

// ---------------- CSR build ----------------
__global__ void k_hist(const int* __restrict__ ei, int* __restrict__ cnt){
  int i = blockIdx.x*256 + threadIdx.x;
  if(i>=ENTOT) return;
  int d = (i<NEDGES)? ei[NEDGES+i] : (i-NEDGES);
  atomicAdd(&cnt[d], 1);
}

#define SCAN_M (NNODES+1)
#define SCAN_NB ((SCAN_M + 2047)/2048)

__global__ void k_scan_a(const int* __restrict__ cnt, int* __restrict__ bsum){
  __shared__ int red[256];
  int b=blockIdx.x, t=threadIdx.x;
  int base = b*2048 + t*8;
  int s=0;
  #pragma unroll
  for(int j=0;j<8;j++){ int idx=base+j; s += (idx<NNODES)? cnt[idx]:0; }
  red[t]=s; __syncthreads();
  for(int o=128;o>0;o>>=1){ if(t<o) red[t]+=red[t+o]; __syncthreads(); }
  if(t==0) bsum[b]=red[0];
}

__global__ void k_scan_b(int* bsum){
  if(threadIdx.x==0){
    int run=0;
    for(int i=0;i<SCAN_NB;i++){ int v=bsum[i]; bsum[i]=run; run+=v; }
  }
}

__global__ void k_scan_c(const int* __restrict__ cnt, const int* __restrict__ bsum,
                         int* __restrict__ row_ptr){
  __shared__ int lds[256];
  int b=blockIdx.x, t=threadIdx.x;
  int base=b*2048+t*8;
  int v[8]; int s=0;
  #pragma unroll
  for(int j=0;j<8;j++){ int idx=base+j; int x=(idx<NNODES)?cnt[idx]:0; v[j]=s; s+=x; }
  lds[t]=s; __syncthreads();
  for(int o=1;o<256;o<<=1){
    int other=0; if(t>=o) other=lds[t-o];
    __syncthreads();
    lds[t]+=other;
    __syncthreads();
  }
  int texcl = lds[t] - s;
  int off0 = bsum[b] + texcl;
  #pragma unroll
  for(int j=0;j<8;j++){ int idx=base+j; if(idx<SCAN_M) row_ptr[idx]=off0+v[j]; }
}

__global__ void k_scatter(const int* __restrict__ ei, const int* __restrict__ row_ptr,
                          int* __restrict__ nxt, int* __restrict__ col){
  int i=blockIdx.x*256+threadIdx.x;
  if(i>=ENTOT) return;
  int s,d;
  if(i<NEDGES){ s=ei[i]; d=ei[NEDGES+i]; } else { s=d=i-NEDGES; }
  int pos = row_ptr[d] + atomicAdd(&nxt[d],1);
  col[pos]=s;
}

// ---------------- tiled GEMM + fused BN/ELU staging + alpha epilogue -------
// Block tile: ROWS x OUTC. Thread tile 4x4 (TX*TY threads active of 256).
// X staged transposed in LDS chunk-wise (KC=32): XT[k][row], float4 reads.
// W resident in LDS row-major [K][OUTC], float4 reads. h output bf16.
template<int K, int OUTC, int HIDC, int ROWS, int TX, int TY, bool XEXT, bool BN>
__global__ __launch_bounds__(256) void k_gemm(
    const void* __restrict__ xin, const void* __restrict__ W,
    const void* __restrict__ avs, const void* __restrict__ avd,
    const float2* __restrict__ bnab,
    u16* __restrict__ hout, float* __restrict__ asrc, float* __restrict__ adst,
    const int* __restrict__ flagp)
{
  const int f = flagp[0];             // external-tensor dtype flag
  constexpr int RP = ROWS+4;
  constexpr int KC = 32;
  __shared__ __align__(16) float WS[K*OUTC];
  __shared__ __align__(16) float XT[KC*RP];
  __shared__ float ared[ROWS][4];     // src_h0, src_h1, dst_h0, dst_h1
  int t=threadIdx.x;
  for(int i=t;i<K*OUTC;i+=256) WS[i]=ldf(W,i,f);
  for(int i=t;i<ROWS*4;i+=256) ((float*)ared)[i]=0.f;
  int row0b = blockIdx.x*ROWS;
  int tx = t%TX, ty=t/TX;
  bool act = (t < TX*TY);
  int c0 = tx*4, r0=ty*4;
  float acc[4][4] = {};

  for(int kb=0; kb<K; kb+=KC){
    __syncthreads();
    // stage XT chunk: ROWS*KC elements, 8 consecutive k's per thread
    constexpr int CPR = KC/8;
    int sr = t/CPR, koff=(t%CPR)*8;
    if(sr < ROWS){
      int grow = row0b + sr;
      float xv8[8];
      if(grow < NNODES){
        if(XEXT && f==1){
          const float4* xp=(const float4*)((const float*)xin + (size_t)grow*K + kb + koff);
          float4 a=xp[0], b=xp[1];
          xv8[0]=a.x;xv8[1]=a.y;xv8[2]=a.z;xv8[3]=a.w;
          xv8[4]=b.x;xv8[5]=b.y;xv8[6]=b.z;xv8[7]=b.w;
        } else {
          uint4 q=*(const uint4*)((const u16*)xin + (size_t)grow*K + kb + koff);
          xv8[0]=b2f(q.x&0xffff); xv8[1]=b2f(q.x>>16);
          xv8[2]=b2f(q.y&0xffff); xv8[3]=b2f(q.y>>16);
          xv8[4]=b2f(q.z&0xffff); xv8[5]=b2f(q.z>>16);
          xv8[6]=b2f(q.w&0xffff); xv8[7]=b2f(q.w>>16);
        }
        if(BN){
          #pragma unroll
          for(int j=0;j<8;j++){
            float2 ab = bnab[kb+koff+j];
            float y = ab.x*xv8[j]+ab.y;
            xv8[j] = y>0.f? y : __expf(y)-1.f;   // ELU
          }
        }
      } else {
        #pragma unroll
        for(int j=0;j<8;j++) xv8[j]=0.f;
      }
      #pragma unroll
      for(int j=0;j<8;j++) XT[(koff+j)*RP + sr] = xv8[j];
    }
    __syncthreads();
    if(act){
      #pragma unroll 8
      for(int kk=0;kk<KC;kk++){
        float4 xv = *(const float4*)&XT[kk*RP + r0];
        float4 wv = *(const float4*)&WS[(kb+kk)*OUTC + c0];
        acc[0][0]+=xv.x*wv.x; acc[0][1]+=xv.x*wv.y; acc[0][2]+=xv.x*wv.z; acc[0][3]+=xv.x*wv.w;
        acc[1][0]+=xv.y*wv.x; acc[1][1]+=xv.y*wv.y; acc[1][2]+=xv.y*wv.z; acc[1][3]+=xv.y*wv.w;
        acc[2][0]+=xv.z*wv.x; acc[2][1]+=xv.z*wv.y; acc[2][2]+=xv.z*wv.z; acc[2][3]+=xv.z*wv.w;
        acc[3][0]+=xv.w*wv.x; acc[3][1]+=xv.w*wv.y; acc[3][2]+=xv.w*wv.z; acc[3][3]+=xv.w*wv.w;
      }
    }
  }
  if(act){
    int head = (c0>=HIDC)?1:0;
    float av4[4], ad4[4];
    #pragma unroll
    for(int j=0;j<4;j++){ av4[j]=ldf(avs,c0+j,f); ad4[j]=ldf(avd,c0+j,f); }
    #pragma unroll
    for(int i=0;i<4;i++){
      float ps=0.f,pd=0.f;
      #pragma unroll
      for(int j=0;j<4;j++){ ps+=acc[i][j]*av4[j]; pd+=acc[i][j]*ad4[j]; }
      atomicAdd(&ared[r0+i][head],ps);
      atomicAdd(&ared[r0+i][2+head],pd);
    }
    #pragma unroll
    for(int i=0;i<4;i++){
      int grow=row0b+r0+i;
      if(grow<NNODES){
        ushort4 pk;
        pk.x=f2b(acc[i][0]); pk.y=f2b(acc[i][1]); pk.z=f2b(acc[i][2]); pk.w=f2b(acc[i][3]);
        *(ushort4*)(hout + (size_t)grow*OUTC + c0) = pk;
      }
    }
  }
  __syncthreads();
  for(int idx=t; idx<ROWS*2; idx+=256){
    int row=idx>>1, h=idx&1; int grow=row0b+row;
    if(grow<NNODES){
      asrc[grow*2+h]=ared[row][h];
      adst[grow*2+h]=ared[row][2+h];
    }
  }
}

// ---------------- per-edge softmax weights (one wave per dst node) --------
__global__ __launch_bounds__(256) void k_alpha(
  const int* __restrict__ row_ptr, const int* __restrict__ col,
  const float2* __restrict__ asrc2, const float2* __restrict__ adst2,
  float2* __restrict__ ab, float2* __restrict__ sinv)
{
  int wave = threadIdx.x>>6, lane=threadIdx.x&63;
  int d = blockIdx.x*4 + wave;
  if(d>=NNODES) return;
  int base=row_ptr[d], deg=row_ptr[d+1]-base;
  float2 adv = adst2[d];
  float m0=-INFINITY, m1=-INFINITY;
  for(int off=0; off<deg; off+=64){
    int j=off+lane;
    if(j<deg){
      float2 s = asrc2[col[base+j]];
      float t0=s.x+adv.x; t0 = t0>0.f? t0 : NEG_SLOPE*t0;
      float t1=s.y+adv.y; t1 = t1>0.f? t1 : NEG_SLOPE*t1;
      ab[base+j]=make_float2(t0,t1);
      m0=fmaxf(m0,t0); m1=fmaxf(m1,t1);
    }
  }
  #pragma unroll
  for(int o=1;o<64;o<<=1){ m0=fmaxf(m0,__shfl_xor(m0,o,64)); m1=fmaxf(m1,__shfl_xor(m1,o,64)); }
  float s0=0.f,s1=0.f;
  for(int off=0; off<deg; off+=64){
    int j=off+lane;
    if(j<deg){
      float2 e=ab[base+j];
      float p0=__expf(e.x-m0), p1=__expf(e.y-m1);
      s0+=p0; s1+=p1;
      ab[base+j]=make_float2(p0,p1);
    }
  }
  #pragma unroll
  for(int o=1;o<64;o<<=1){ s0+=__shfl_xor(s0,o,64); s1+=__shfl_xor(s1,o,64); }
  if(lane==0){
    float i0 = s0>0.f?1.0f/s0:0.f, i1 = s1>0.f?1.0f/s1:0.f;
    sinv[d]=make_float2(i0,i1);
  }
}

// ---------------- gather-accumulate aggregation ---------------------------
// one wave per dst node, lane = channel, 4 edges in flight.
template<int OUTC, bool FINAL>
__global__ __launch_bounds__(256) void k_agg2(
  const int* __restrict__ row_ptr, const int* __restrict__ col,
  const u16* __restrict__ hin, const float2* __restrict__ ab,
  const float2* __restrict__ sinvp, const void* __restrict__ bias,
  u16* __restrict__ houtb, void* __restrict__ outv, const int* __restrict__ flagp)
{
  const int f = flagp[0];
  int wave = threadIdx.x>>6, lane=threadIdx.x&63;
  int d = blockIdx.x*4 + wave;
  if(d>=NNODES) return;
  int base=row_ptr[d], deg=row_ptr[d+1]-base;
  float acc=0.f, acc2=0.f;
  for(int j=0;j<deg;j+=4){
    int cs[4]; float2 al[4];
    #pragma unroll
    for(int u=0;u<4;u++){
      int jj=j+u; bool v = jj<deg;
      int idx = base + (v? jj : j);
      cs[u]=col[idx];
      al[u]= v? ab[idx] : make_float2(0.f,0.f);
    }
    #pragma unroll
    for(int u=0;u<4;u++){
      float h = b2f(hin[(size_t)cs[u]*OUTC + lane]);
      float p = FINAL ? (lane<40? al[u].x : al[u].y)
                      : (lane<32? al[u].x : al[u].y);
      acc += p*h;
      if(FINAL && lane<16)
        acc2 += al[u].y * b2f(hin[(size_t)cs[u]*OUTC + 64 + lane]);
    }
  }
  float2 sv = sinvp[d];
  if(!FINAL){
    float val = acc*(lane<32? sv.x: sv.y) + ldf(bias,lane,f);
    houtb[(size_t)d*OUTC + lane] = f2b(val);
  } else {
    float valA = acc*(lane<40? sv.x: sv.y);
    float valB = acc2*sv.y;
    int co=lane;
    float oA = __shfl(valA, (40+co)&63, 64);  // head1 out-ch co (co<24)
    float oB = __shfl(valB, (co+40)&63, 64);  // head1 out-ch co (co>=24)
    if(co<40){
      float h1v = (co<24)? oA : oB;
      float res = 0.5f*(valA + h1v) + ldf(bias,co,f);
      if(f) ((float*)outv)[(size_t)d*40+co] = res;
      else  ((__hip_bfloat16*)outv)[(size_t)d*40+co] = __float2bfloat16(res);
    }
  }
}

// ---------------- batch norm (stats + coefficient finalize) ---------------
__global__ __launch_bounds__(256) void k_bnstats(const u16* __restrict__ h, float* __restrict__ stats){
  __shared__ float red[4][128];
  int t=threadIdx.x; int c=t&63; int g=t>>6;
  float s=0.f,q=0.f;
  for(int r=blockIdx.x*4+g; r<NNODES; r+=gridDim.x*4){
    float v=b2f(h[(size_t)r*64+c]); s+=v; q+=v*v;
  }
  red[g][c]=s; red[g][64+c]=q;
  __syncthreads();
  if(t<128){
    float tot=red[0][t]+red[1][t]+red[2][t]+red[3][t];
    atomicAdd(&stats[t], tot);
  }
}

__global__ void k_bnfinal(const float* __restrict__ stats,
                          const void* __restrict__ gm, const void* __restrict__ bt,
                          float2* __restrict__ bnab, const int* __restrict__ flagp){
  const int f = flagp[0];
  int c=threadIdx.x;
  if(c>=64) return;
  float mu=stats[c]*(1.0f/NNODES);
  float var=stats[64+c]*(1.0f/NNODES)-mu*mu;
  var = var>0.f?var:0.f;
  float A = ldf(gm,c,f)*rsqrtf(var+BN_EPS);
  float B = ldf(bt,c,f) - A*mu;
  bnab[c]=make_float2(A,B);
}

extern "C" void kernel_launch(void* const* d_in, const int* in_sizes, int n_in,
                              void* d_out, int out_size, void* d_ws, size_t ws_size,
                              hipStream_t stream){
  const void* x  =d_in[0];
  const int* ei =(const int*)d_in[1];
  const void* W0 =d_in[2];  const void* as0=d_in[3];  const void* ad0=d_in[4];
  const void* b0 =d_in[5];  const void* g0 =d_in[6];  const void* bt0=d_in[7];
  const void* W1 =d_in[8];  const void* as1=d_in[9];  const void* ad1=d_in[10];
  const void* b1 =d_in[11]; const void* g1 =d_in[12]; const void* bt1=d_in[13];
  const void* W2 =d_in[14]; const void* as2=d_in[15]; const void* ad2=d_in[16];
  const void* b2 =d_in[17];

  char* ws=(char*)d_ws;
  size_t off=0;
  auto alloc=[&](size_t bytes)->void*{ void* p=ws+off; off+=(bytes+255)&~(size_t)255; return p; };
  int*    flag   =(int*)   alloc(256);
  int*    row_ptr=(int*)   alloc((size_t)(NNODES+1)*4);
  int*    cnt    =(int*)   alloc((size_t)NNODES*4);
  int*    colx   =(int*)   alloc((size_t)ENTOT*4);
  int*    bsum   =(int*)   alloc((size_t)SCAN_NB*4);
  u16*    hA     =(u16*)   alloc((size_t)100032*80*2);   // gemm outputs (64 or 80 ch)
  u16*    hB0    =(u16*)   alloc((size_t)100032*64*2);   // agg outputs (pre-BN)
  u16*    hB1    =(u16*)   alloc((size_t)100032*64*2);
  float*  asrc   =(float*) alloc((size_t)NNODES*2*4);
  float*  adst   =(float*) alloc((size_t)NNODES*2*4);
  float2* abuf   =(float2*)alloc((size_t)ENTOT*8);       // per-edge softmax weights
  float2* sinv   =(float2*)alloc((size_t)NNODES*8);      // per-node 1/sum
  float*  stats  =(float*) alloc(128*4);
  float2* bnab   =(float2*)alloc(64*8);

  k_detect<<<1,256,0,stream>>>((const u16*)x, flag);

  // CSR by destination (shared by all 3 layers)
  hipMemsetAsync(cnt,0,(size_t)NNODES*4,stream);
  int gE=(ENTOT+255)/256;
  k_hist   <<<gE,256,0,stream>>>(ei,cnt);
  k_scan_a <<<SCAN_NB,256,0,stream>>>(cnt,bsum);
  k_scan_b <<<1,64,0,stream>>>(bsum);
  k_scan_c <<<SCAN_NB,256,0,stream>>>(cnt,bsum,row_ptr);
  hipMemsetAsync(cnt,0,(size_t)NNODES*4,stream);
  k_scatter<<<gE,256,0,stream>>>(ei,row_ptr,cnt,colx);

  int gN = (NNODES+3)/4;    // node-wave kernels
  // ---- layer 0: x(128,ext) -> hA(64) ----
  k_gemm<128,64,32,64,16,16,true ,false><<<(NNODES+63)/64,256,0,stream>>>(
      x,W0,as0,ad0,nullptr,hA,asrc,adst,flag);
  k_alpha<<<gN,256,0,stream>>>(row_ptr,colx,(const float2*)asrc,(const float2*)adst,abuf,sinv);
  k_agg2<64,false><<<gN,256,0,stream>>>(row_ptr,colx,hA,abuf,sinv,b0,hB0,nullptr,flag);
  hipMemsetAsync(stats,0,512,stream);
  k_bnstats<<<256,256,0,stream>>>(hB0,stats);
  k_bnfinal<<<1,64,0,stream>>>(stats,g0,bt0,bnab,flag);
  // ---- layer 1: hB0(+BN/ELU fused) -> hA(64) ----
  k_gemm<64,64,32,64,16,16,false,true ><<<(NNODES+63)/64,256,0,stream>>>(
      hB0,W1,as1,ad1,bnab,hA,asrc,adst,flag);
  k_alpha<<<gN,256,0,stream>>>(row_ptr,colx,(const float2*)asrc,(const float2*)adst,abuf,sinv);
  k_agg2<64,false><<<gN,256,0,stream>>>(row_ptr,colx,hA,abuf,sinv,b1,hB1,nullptr,flag);
  hipMemsetAsync(stats,0,512,stream);
  k_bnstats<<<256,256,0,stream>>>(hB1,stats);
  k_bnfinal<<<1,64,0,stream>>>(stats,g1,bt1,bnab,flag);
  // ---- layer 2: hB1(+BN/ELU fused) -> hA(80) -> out (head mean) ----
  k_gemm<64,80,40,48,20,12,false,true ><<<(NNODES+47)/48,256,0,stream>>>(
      hB1,W2,as2,ad2,bnab,hA,asrc,adst,flag);
  k_alpha<<<gN,256,0,stream>>>(row_ptr,colx,(const float2*)asrc,(const float2*)adst,abuf,sinv);
  k_agg2<80,true ><<<gN,256,0,stream>>>(row_ptr,colx,hA,abuf,sinv,b2,nullptr,d_out,flag);

  (void)in_sizes;(void)n_in;(void)out_size;(void)ws_size;
}

// Round 4
// 724.298 us; speedup vs baseline: 1.4682x; 1.4682x over previous
//
#include <hip/hip_runtime.h>
#include <hip/hip_bf16.h>
#include <math.h>

// GAT: N=100000 nodes, E=1600000 edges (+N self loops), 3 layers.
// Inputs bf16 (runtime-detected flag kept). Intermediates bf16.
// Softmax: shift-invariant -> no segment-max pass (logits ~N(0,1), clamp 60).

#define NNODES 100000
#define NEDGES 1600000
#define ENTOT  (NEDGES + NNODES)
#define NEG_SLOPE 0.2f
#define BN_EPS 1e-5f

typedef unsigned short u16;
typedef unsigned int u32;

__device__ __forceinline__ float b2f(u16 u){ union{u32 i; float f;} v; v.i=((u32)u)<<16; return v.f; }
__device__ __forceinline__ u16 f2b(float x){ __hip_bfloat16 b=__float2bfloat16(x); return *(u16*)&b; }
__device__ __forceinline__ float ldf(const void* p, int i, int f){
  return f ? ((const float*)p)[i] : b2f(((const u16*)p)[i]);
}

// ---------------- dtype probe ----------------
__global__ void k_detect(const u16* __restrict__ x, int* __restrict__ flag){
  __shared__ int bad;
  if(threadIdx.x==0) bad=0;
  __syncthreads();
  int cnt=0;
  for(int i=threadIdx.x;i<4096;i+=256){
    u16 v = x[2*i];
    int ex = (v>>7)&0xff;
    if(ex==0xff || (ex==0 && (v&0x7fff)!=0)) cnt++;
  }
  atomicAdd(&bad,cnt);
  __syncthreads();
  if(threadIdx.x==0) flag[0] = (bad>4)?1:0;   // 1 = fp32, 0 = bf16
}

// ---------------- CSR build ----------------
__global__ void k_hist(const int* __restrict__ ei, int* __restrict__ cnt){
  int i = blockIdx.x*256 + threadIdx.x;
  if(i>=ENTOT) return;
  int d = (i<NEDGES)? ei[NEDGES+i] : (i-NEDGES);
  atomicAdd(&cnt[d], 1);
}

#define SCAN_M (NNODES+1)
#define SCAN_NB ((SCAN_M + 2047)/2048)

__global__ void k_scan_a(const int* __restrict__ cnt, int* __restrict__ bsum){
  __shared__ int red[256];
  int b=blockIdx.x, t=threadIdx.x;
  int base = b*2048 + t*8;
  int s=0;
  #pragma unroll
  for(int j=0;j<8;j++){ int idx=base+j; s += (idx<NNODES)? cnt[idx]:0; }
  red[t]=s; __syncthreads();
  for(int o=128;o>0;o>>=1){ if(t<o) red[t]+=red[t+o]; __syncthreads(); }
  if(t==0) bsum[b]=red[0];
}

__global__ void k_scan_b(int* bsum){
  if(threadIdx.x==0){
    int run=0;
    for(int i=0;i<SCAN_NB;i++){ int v=bsum[i]; bsum[i]=run; run+=v; }
  }
}

__global__ void k_scan_c(const int* __restrict__ cnt, const int* __restrict__ bsum,
                         int* __restrict__ row_ptr){
  __shared__ int lds[256];
  int b=blockIdx.x, t=threadIdx.x;
  int base=b*2048+t*8;
  int v[8]; int s=0;
  #pragma unroll
  for(int j=0;j<8;j++){ int idx=base+j; int x=(idx<NNODES)?cnt[idx]:0; v[j]=s; s+=x; }
  lds[t]=s; __syncthreads();
  for(int o=1;o<256;o<<=1){
    int other=0; if(t>=o) other=lds[t-o];
    __syncthreads();
    lds[t]+=other;
    __syncthreads();
  }
  int texcl = lds[t] - s;
  int off0 = bsum[b] + texcl;
  #pragma unroll
  for(int j=0;j<8;j++){ int idx=base+j; if(idx<SCAN_M) row_ptr[idx]=off0+v[j]; }
}

__global__ void k_scatter(const int* __restrict__ ei, const int* __restrict__ row_ptr,
                          int* __restrict__ nxt, int* __restrict__ col){
  int i=blockIdx.x*256+threadIdx.x;
  if(i>=ENTOT) return;
  int s,d;
  if(i<NEDGES){ s=ei[i]; d=ei[NEDGES+i]; } else { s=d=i-NEDGES; }
  int pos = row_ptr[d] + atomicAdd(&nxt[d],1);
  col[pos]=s;
}

// ---------------- tiled GEMM + fused BN/ELU staging + alpha epilogue -------
template<int K, int OUTC, int HIDC, int ROWS, int TX, int TY, bool XEXT, bool BN>
__global__ __launch_bounds__(256) void k_gemm(
    const void* __restrict__ xin, const void* __restrict__ W,
    const void* __restrict__ avs, const void* __restrict__ avd,
    const float2* __restrict__ bnab,
    u16* __restrict__ hout, float* __restrict__ asrc, float* __restrict__ adst,
    const int* __restrict__ flagp)
{
  const int f = flagp[0];
  constexpr int RP = ROWS+4;
  constexpr int KC = 32;
  __shared__ __align__(16) float WS[K*OUTC];
  __shared__ __align__(16) float XT[KC*RP];
  __shared__ float ared[ROWS][4];
  int t=threadIdx.x;
  for(int i=t;i<K*OUTC;i+=256) WS[i]=ldf(W,i,f);
  for(int i=t;i<ROWS*4;i+=256) ((float*)ared)[i]=0.f;
  int row0b = blockIdx.x*ROWS;
  int tx = t%TX, ty=t/TX;
  bool act = (t < TX*TY);
  int c0 = tx*4, r0=ty*4;
  float acc[4][4] = {};

  for(int kb=0; kb<K; kb+=KC){
    __syncthreads();
    constexpr int CPR = KC/8;
    int sr = t/CPR, koff=(t%CPR)*8;
    if(sr < ROWS){
      int grow = row0b + sr;
      float xv8[8];
      if(grow < NNODES){
        if(XEXT && f==1){
          const float4* xp=(const float4*)((const float*)xin + (size_t)grow*K + kb + koff);
          float4 a=xp[0], b=xp[1];
          xv8[0]=a.x;xv8[1]=a.y;xv8[2]=a.z;xv8[3]=a.w;
          xv8[4]=b.x;xv8[5]=b.y;xv8[6]=b.z;xv8[7]=b.w;
        } else {
          uint4 q=*(const uint4*)((const u16*)xin + (size_t)grow*K + kb + koff);
          xv8[0]=b2f(q.x&0xffff); xv8[1]=b2f(q.x>>16);
          xv8[2]=b2f(q.y&0xffff); xv8[3]=b2f(q.y>>16);
          xv8[4]=b2f(q.z&0xffff); xv8[5]=b2f(q.z>>16);
          xv8[6]=b2f(q.w&0xffff); xv8[7]=b2f(q.w>>16);
        }
        if(BN){
          #pragma unroll
          for(int j=0;j<8;j++){
            float2 ab = bnab[kb+koff+j];
            float y = ab.x*xv8[j]+ab.y;
            xv8[j] = y>0.f? y : __expf(y)-1.f;   // ELU
          }
        }
      } else {
        #pragma unroll
        for(int j=0;j<8;j++) xv8[j]=0.f;
      }
      #pragma unroll
      for(int j=0;j<8;j++) XT[(koff+j)*RP + sr] = xv8[j];
    }
    __syncthreads();
    if(act){
      #pragma unroll 8
      for(int kk=0;kk<KC;kk++){
        float4 xv = *(const float4*)&XT[kk*RP + r0];
        float4 wv = *(const float4*)&WS[(kb+kk)*OUTC + c0];
        acc[0][0]+=xv.x*wv.x; acc[0][1]+=xv.x*wv.y; acc[0][2]+=xv.x*wv.z; acc[0][3]+=xv.x*wv.w;
        acc[1][0]+=xv.y*wv.x; acc[1][1]+=xv.y*wv.y; acc[1][2]+=xv.y*wv.z; acc[1][3]+=xv.y*wv.w;
        acc[2][0]+=xv.z*wv.x; acc[2][1]+=xv.z*wv.y; acc[2][2]+=xv.z*wv.z; acc[2][3]+=xv.z*wv.w;
        acc[3][0]+=xv.w*wv.x; acc[3][1]+=xv.w*wv.y; acc[3][2]+=xv.w*wv.z; acc[3][3]+=xv.w*wv.w;
      }
    }
  }
  if(act){
    int head = (c0>=HIDC)?1:0;
    float av4[4], ad4[4];
    #pragma unroll
    for(int j=0;j<4;j++){ av4[j]=ldf(avs,c0+j,f); ad4[j]=ldf(avd,c0+j,f); }
    #pragma unroll
    for(int i=0;i<4;i++){
      float ps=0.f,pd=0.f;
      #pragma unroll
      for(int j=0;j<4;j++){ ps+=acc[i][j]*av4[j]; pd+=acc[i][j]*ad4[j]; }
      atomicAdd(&ared[r0+i][head],ps);
      atomicAdd(&ared[r0+i][2+head],pd);
    }
    #pragma unroll
    for(int i=0;i<4;i++){
      int grow=row0b+r0+i;
      if(grow<NNODES){
        ushort4 pk;
        pk.x=f2b(acc[i][0]); pk.y=f2b(acc[i][1]); pk.z=f2b(acc[i][2]); pk.w=f2b(acc[i][3]);
        *(ushort4*)(hout + (size_t)grow*OUTC + c0) = pk;
      }
    }
  }
  __syncthreads();
  for(int idx=t; idx<ROWS*2; idx+=256){
    int row=idx>>1, h=idx&1; int grow=row0b+row;
    if(grow<NNODES){
      asrc[grow*2+h]=ared[row][h];
      adst[grow*2+h]=ared[row][2+h];
    }
  }
}

// ---------------- fused softmax + gather-aggregate -------------------------
// One wave per dst node. 8 edge slots x 8 lanes; lane loads ushort4 pairs.
// p = exp(leakyrelu(asrc+adst)) (no max shift; clamp 60); normalize at end.
template<int OUTC, bool FINAL>
__global__ __launch_bounds__(256) void k_aggf(
  const int* __restrict__ row_ptr, const int* __restrict__ col,
  const u16* __restrict__ hin, const float2* __restrict__ asrc2,
  const float2* __restrict__ adst2, const void* __restrict__ bias,
  u16* __restrict__ houtb, void* __restrict__ outv, const int* __restrict__ flagp)
{
  const int f = flagp[0];
  __shared__ float vbuf[4][80];
  int wave = threadIdx.x>>6, lane=threadIdx.x&63;
  int d = blockIdx.x*4 + wave;        // NNODES % 4 == 0 -> always valid
  int base=row_ptr[d], deg=row_ptr[d+1]-base;
  int slot=lane>>3, cg=lane&7;
  float2 adv = adst2[d];
  float acc0[4]={0.f,0.f,0.f,0.f}, acc1[4]={0.f,0.f,0.f,0.f}, accx[2]={0.f,0.f};
  float s0=0.f, s1=0.f;
  for(int j=0;j<deg;j+=8){
    int jj=j+slot;
    bool valid = jj<deg;
    int cs = col[base + (valid? jj : 0)];
    if(valid){
      float2 sv = asrc2[cs];
      float e0=sv.x+adv.x; e0 = e0>0.f? e0 : NEG_SLOPE*e0; e0=fminf(e0,60.f);
      float e1=sv.y+adv.y; e1 = e1>0.f? e1 : NEG_SLOPE*e1; e1=fminf(e1,60.f);
      float p0=__expf(e0), p1=__expf(e1);
      s0+=p0; s1+=p1;
      const u16* hp = hin + (size_t)cs*OUTC;
      ushort4 ha = *(const ushort4*)(hp + cg*4);
      ushort4 hb = *(const ushort4*)(hp + 32 + cg*4);
      // head per sub-block: concat channels [0,HID) head0, rest head1
      float pa = p0;
      float pb = FINAL ? ((cg<2)? p0 : p1) : p1;   // FINAL: ch32..39 head0
      acc0[0]+=pa*b2f(ha.x); acc0[1]+=pa*b2f(ha.y); acc0[2]+=pa*b2f(ha.z); acc0[3]+=pa*b2f(ha.w);
      acc1[0]+=pb*b2f(hb.x); acc1[1]+=pb*b2f(hb.y); acc1[2]+=pb*b2f(hb.z); acc1[3]+=pb*b2f(hb.w);
      if(FINAL){
        ushort2 hc = *(const ushort2*)(hp + 64 + cg*2);
        accx[0]+=p1*b2f(hc.x); accx[1]+=p1*b2f(hc.y);
      }
    }
  }
  // combine the 8 slots (xor over lane bits 3..5)
  #pragma unroll
  for(int o=8;o<64;o<<=1){
    s0+=__shfl_xor(s0,o,64); s1+=__shfl_xor(s1,o,64);
    #pragma unroll
    for(int k=0;k<4;k++){ acc0[k]+=__shfl_xor(acc0[k],o,64); acc1[k]+=__shfl_xor(acc1[k],o,64); }
    if(FINAL){ accx[0]+=__shfl_xor(accx[0],o,64); accx[1]+=__shfl_xor(accx[1],o,64); }
  }
  float inv0 = s0>0.f?1.f/s0:0.f, inv1 = s1>0.f?1.f/s1:0.f;
  if(!FINAL){
    if(slot==0){
      ushort4 o0,o1;
      o0.x=f2b(acc0[0]*inv0 + ldf(bias,cg*4+0,f));
      o0.y=f2b(acc0[1]*inv0 + ldf(bias,cg*4+1,f));
      o0.z=f2b(acc0[2]*inv0 + ldf(bias,cg*4+2,f));
      o0.w=f2b(acc0[3]*inv0 + ldf(bias,cg*4+3,f));
      o1.x=f2b(acc1[0]*inv1 + ldf(bias,32+cg*4+0,f));
      o1.y=f2b(acc1[1]*inv1 + ldf(bias,32+cg*4+1,f));
      o1.z=f2b(acc1[2]*inv1 + ldf(bias,32+cg*4+2,f));
      o1.w=f2b(acc1[3]*inv1 + ldf(bias,32+cg*4+3,f));
      *(ushort4*)(houtb + (size_t)d*64 + cg*4)      = o0;
      *(ushort4*)(houtb + (size_t)d*64 + 32 + cg*4) = o1;
    }
  } else {
    if(slot==0){
      #pragma unroll
      for(int k=0;k<4;k++){
        int c  = cg*4+k;
        int c2 = 32+cg*4+k;
        vbuf[wave][c]  = acc0[k]*inv0;                      // ch<32: head0
        vbuf[wave][c2] = acc1[k]*((c2<40)?inv0:inv1);
      }
      vbuf[wave][64+cg*2]   = accx[0]*inv1;
      vbuf[wave][64+cg*2+1] = accx[1]*inv1;
    }
    __syncthreads();
    if(lane<40){
      float res = 0.5f*(vbuf[wave][lane] + vbuf[wave][40+lane]) + ldf(bias,lane,f);
      if(f) ((float*)outv)[(size_t)d*40+lane] = res;
      else  ((__hip_bfloat16*)outv)[(size_t)d*40+lane] = __float2bfloat16(res);
    }
  }
}

// ---------------- batch norm (stats + coefficient finalize) ---------------
__global__ __launch_bounds__(256) void k_bnstats(const u16* __restrict__ h, float* __restrict__ stats){
  __shared__ float red[4][128];
  int t=threadIdx.x; int c=t&63; int g=t>>6;
  float s=0.f,q=0.f;
  for(int r=blockIdx.x*4+g; r<NNODES; r+=gridDim.x*4){
    float v=b2f(h[(size_t)r*64+c]); s+=v; q+=v*v;
  }
  red[g][c]=s; red[g][64+c]=q;
  __syncthreads();
  if(t<128){
    float tot=red[0][t]+red[1][t]+red[2][t]+red[3][t];
    atomicAdd(&stats[t], tot);
  }
}

__global__ void k_bnfinal(const float* __restrict__ stats,
                          const void* __restrict__ gm, const void* __restrict__ bt,
                          float2* __restrict__ bnab, const int* __restrict__ flagp){
  const int f = flagp[0];
  int c=threadIdx.x;
  if(c>=64) return;
  float mu=stats[c]*(1.0f/NNODES);
  float var=stats[64+c]*(1.0f/NNODES)-mu*mu;
  var = var>0.f?var:0.f;
  float A = ldf(gm,c,f)*rsqrtf(var+BN_EPS);
  float B = ldf(bt,c,f) - A*mu;
  bnab[c]=make_float2(A,B);
}

extern "C" void kernel_launch(void* const* d_in, const int* in_sizes, int n_in,
                              void* d_out, int out_size, void* d_ws, size_t ws_size,
                              hipStream_t stream){
  const void* x  =d_in[0];
  const int* ei =(const int*)d_in[1];
  const void* W0 =d_in[2];  const void* as0=d_in[3];  const void* ad0=d_in[4];
  const void* b0 =d_in[5];  const void* g0 =d_in[6];  const void* bt0=d_in[7];
  const void* W1 =d_in[8];  const void* as1=d_in[9];  const void* ad1=d_in[10];
  const void* b1 =d_in[11]; const void* g1 =d_in[12]; const void* bt1=d_in[13];
  const void* W2 =d_in[14]; const void* as2=d_in[15]; const void* ad2=d_in[16];
  const void* b2 =d_in[17];

  char* ws=(char*)d_ws;
  size_t off=0;
  auto alloc=[&](size_t bytes)->void*{ void* p=ws+off; off+=(bytes+255)&~(size_t)255; return p; };
  int*    flag   =(int*)   alloc(256);
  int*    row_ptr=(int*)   alloc((size_t)(NNODES+1)*4);
  int*    cnt    =(int*)   alloc((size_t)NNODES*4);
  int*    colx   =(int*)   alloc((size_t)ENTOT*4);
  int*    bsum   =(int*)   alloc((size_t)SCAN_NB*4);
  u16*    hA     =(u16*)   alloc((size_t)100032*80*2);   // gemm outputs (64 or 80 ch)
  u16*    hB0    =(u16*)   alloc((size_t)100032*64*2);   // agg outputs (pre-BN)
  u16*    hB1    =(u16*)   alloc((size_t)100032*64*2);
  float*  asrc   =(float*) alloc((size_t)NNODES*2*4);
  float*  adst   =(float*) alloc((size_t)NNODES*2*4);
  float*  stats  =(float*) alloc(128*4);
  float2* bnab   =(float2*)alloc(64*8);

  k_detect<<<1,256,0,stream>>>((const u16*)x, flag);

  // CSR by destination (shared by all 3 layers)
  hipMemsetAsync(cnt,0,(size_t)NNODES*4,stream);
  int gE=(ENTOT+255)/256;
  k_hist   <<<gE,256,0,stream>>>(ei,cnt);
  k_scan_a <<<SCAN_NB,256,0,stream>>>(cnt,bsum);
  k_scan_b <<<1,64,0,stream>>>(bsum);
  k_scan_c <<<SCAN_NB,256,0,stream>>>(cnt,bsum,row_ptr);
  hipMemsetAsync(cnt,0,(size_t)NNODES*4,stream);
  k_scatter<<<gE,256,0,stream>>>(ei,row_ptr,cnt,colx);

  int gN = NNODES/4;    // 25000 blocks, 4 node-waves each (NNODES%4==0)
  // ---- layer 0 ----
  k_gemm<128,64,32,64,16,16,true ,false><<<(NNODES+63)/64,256,0,stream>>>(
      x,W0,as0,ad0,nullptr,hA,asrc,adst,flag);
  k_aggf<64,false><<<gN,256,0,stream>>>(row_ptr,colx,hA,
      (const float2*)asrc,(const float2*)adst,b0,hB0,nullptr,flag);
  hipMemsetAsync(stats,0,512,stream);
  k_bnstats<<<256,256,0,stream>>>(hB0,stats);
  k_bnfinal<<<1,64,0,stream>>>(stats,g0,bt0,bnab,flag);
  // ---- layer 1 ----
  k_gemm<64,64,32,64,16,16,false,true ><<<(NNODES+63)/64,256,0,stream>>>(
      hB0,W1,as1,ad1,bnab,hA,asrc,adst,flag);
  k_aggf<64,false><<<gN,256,0,stream>>>(row_ptr,colx,hA,
      (const float2*)asrc,(const float2*)adst,b1,hB1,nullptr,flag);
  hipMemsetAsync(stats,0,512,stream);
  k_bnstats<<<256,256,0,stream>>>(hB1,stats);
  k_bnfinal<<<1,64,0,stream>>>(stats,g1,bt1,bnab,flag);
  // ---- layer 2 (head mean -> d_out) ----
  k_gemm<64,80,40,48,20,12,false,true ><<<(NNODES+47)/48,256,0,stream>>>(
      hB1,W2,as2,ad2,bnab,hA,asrc,adst,flag);
  k_aggf<80,true ><<<gN,256,0,stream>>>(row_ptr,colx,hA,
      (const float2*)asrc,(const float2*)adst,b2,nullptr,d_out,flag);

  (void)in_sizes;(void)n_in;(void)out_size;(void)ws_size;
}

// Round 5
// 688.724 us; speedup vs baseline: 1.5440x; 1.0517x over previous
//
#include <hip/hip_runtime.h>
#include <hip/hip_bf16.h>
#include <math.h>

// GAT: N=100000 nodes, E=1600000 edges (+N self loops), 3 layers.
// Inputs bf16 (runtime-detected flag kept). Intermediates bf16.
// Softmax: shift-invariant -> no segment-max pass (logits small, clamp 60).
// Scatter: XCD-partitioned (blockIdx%8 round-robin) to kill 64B-sector
// write amplification (was 109 MB WRITE for a 6.8 MB array).

#define NNODES 100000
#define NEDGES 1600000
#define ENTOT  (NEDGES + NNODES)
#define NEG_SLOPE 0.2f
#define BN_EPS 1e-5f

#define NRANGE 8
#define RSIZE  (NNODES/NRANGE)     // 12500
#define SCHUNKS 128

typedef unsigned short u16;
typedef unsigned int u32;

__device__ __forceinline__ float b2f(u16 u){ union{u32 i; float f;} v; v.i=((u32)u)<<16; return v.f; }
__device__ __forceinline__ u16 f2b(float x){ __hip_bfloat16 b=__float2bfloat16(x); return *(u16*)&b; }
__device__ __forceinline__ float ldf(const void* p, int i, int f){
  return f ? ((const float*)p)[i] : b2f(((const u16*)p)[i]);
}

// ---------------- dtype probe ----------------
__global__ void k_detect(const u16* __restrict__ x, int* __restrict__ flag){
  __shared__ int bad;
  if(threadIdx.x==0) bad=0;
  __syncthreads();
  int cnt=0;
  for(int i=threadIdx.x;i<4096;i+=256){
    u16 v = x[2*i];
    int ex = (v>>7)&0xff;
    if(ex==0xff || (ex==0 && (v&0x7fff)!=0)) cnt++;
  }
  atomicAdd(&bad,cnt);
  __syncthreads();
  if(threadIdx.x==0) flag[0] = (bad>4)?1:0;   // 1 = fp32, 0 = bf16
}

// ---------------- CSR build ----------------
__global__ void k_hist(const int* __restrict__ ei, int* __restrict__ cnt){
  int i = blockIdx.x*256 + threadIdx.x;
  if(i>=ENTOT) return;
  int d = (i<NEDGES)? ei[NEDGES+i] : (i-NEDGES);
  atomicAdd(&cnt[d], 1);
}

#define SCAN_M (NNODES+1)
#define SCAN_NB ((SCAN_M + 2047)/2048)

__global__ void k_scan_a(const int* __restrict__ cnt, int* __restrict__ bsum){
  __shared__ int red[256];
  int b=blockIdx.x, t=threadIdx.x;
  int base = b*2048 + t*8;
  int s=0;
  #pragma unroll
  for(int j=0;j<8;j++){ int idx=base+j; s += (idx<NNODES)? cnt[idx]:0; }
  red[t]=s; __syncthreads();
  for(int o=128;o>0;o>>=1){ if(t<o) red[t]+=red[t+o]; __syncthreads(); }
  if(t==0) bsum[b]=red[0];
}

__global__ void k_scan_b(int* bsum){
  if(threadIdx.x==0){
    int run=0;
    for(int i=0;i<SCAN_NB;i++){ int v=bsum[i]; bsum[i]=run; run+=v; }
  }
}

__global__ void k_scan_c(const int* __restrict__ cnt, const int* __restrict__ bsum,
                         int* __restrict__ row_ptr){
  __shared__ int lds[256];
  int b=blockIdx.x, t=threadIdx.x;
  int base=b*2048+t*8;
  int v[8]; int s=0;
  #pragma unroll
  for(int j=0;j<8;j++){ int idx=base+j; int x=(idx<NNODES)?cnt[idx]:0; v[j]=s; s+=x; }
  lds[t]=s; __syncthreads();
  for(int o=1;o<256;o<<=1){
    int other=0; if(t>=o) other=lds[t-o];
    __syncthreads();
    lds[t]+=other;
    __syncthreads();
  }
  int texcl = lds[t] - s;
  int off0 = bsum[b] + texcl;
  #pragma unroll
  for(int j=0;j<8;j++){ int idx=base+j; if(idx<SCAN_M) row_ptr[idx]=off0+v[j]; }
}

// XCD-partitioned scatter: block (chunk, range) writes only dsts in its range.
// blockIdx%8 ~ XCD (round-robin heuristic) -> col-line writes stay in one L2.
__global__ __launch_bounds__(256) void k_scatter2(
    const int* __restrict__ ei, const int* __restrict__ row_ptr,
    int* __restrict__ nxt, int* __restrict__ col){
  int r = blockIdx.x & (NRANGE-1);
  int c = blockIdx.x >> 3;
  int lo = r*RSIZE, hi = lo+RSIZE;
  const int CH = (ENTOT + SCHUNKS-1)/SCHUNKS;
  int beg = c*CH, end = beg+CH; if(end>ENTOT) end=ENTOT;
  for(int i=beg+threadIdx.x; i<end; i+=256){
    int d = (i<NEDGES)? ei[NEDGES+i] : (i-NEDGES);
    if(d>=lo && d<hi){
      int s = (i<NEDGES)? ei[i] : d;
      int pos = row_ptr[d] + atomicAdd(&nxt[d],1);
      col[pos]=s;
    }
  }
}

// ---------------- tiled GEMM + fused BN/ELU staging + alpha epilogue -------
template<int K, int OUTC, int HIDC, int ROWS, int TX, int TY, bool XEXT, bool BN>
__global__ __launch_bounds__(256) void k_gemm(
    const void* __restrict__ xin, const void* __restrict__ W,
    const void* __restrict__ avs, const void* __restrict__ avd,
    const float2* __restrict__ bnab,
    u16* __restrict__ hout, float* __restrict__ asrc, float* __restrict__ adst,
    const int* __restrict__ flagp)
{
  const int f = flagp[0];
  constexpr int RP = ROWS+4;
  constexpr int KC = 32;
  __shared__ __align__(16) float WS[K*OUTC];
  __shared__ __align__(16) float XT[KC*RP];
  __shared__ float ared[ROWS][4];
  int t=threadIdx.x;
  for(int i=t;i<K*OUTC;i+=256) WS[i]=ldf(W,i,f);
  for(int i=t;i<ROWS*4;i+=256) ((float*)ared)[i]=0.f;
  int row0b = blockIdx.x*ROWS;
  int tx = t%TX, ty=t/TX;
  bool act = (t < TX*TY);
  int c0 = tx*4, r0=ty*4;
  float acc[4][4] = {};

  for(int kb=0; kb<K; kb+=KC){
    __syncthreads();
    constexpr int CPR = KC/8;
    int sr = t/CPR, koff=(t%CPR)*8;
    if(sr < ROWS){
      int grow = row0b + sr;
      float xv8[8];
      if(grow < NNODES){
        if(XEXT && f==1){
          const float4* xp=(const float4*)((const float*)xin + (size_t)grow*K + kb + koff);
          float4 a=xp[0], b=xp[1];
          xv8[0]=a.x;xv8[1]=a.y;xv8[2]=a.z;xv8[3]=a.w;
          xv8[4]=b.x;xv8[5]=b.y;xv8[6]=b.z;xv8[7]=b.w;
        } else {
          uint4 q=*(const uint4*)((const u16*)xin + (size_t)grow*K + kb + koff);
          xv8[0]=b2f(q.x&0xffff); xv8[1]=b2f(q.x>>16);
          xv8[2]=b2f(q.y&0xffff); xv8[3]=b2f(q.y>>16);
          xv8[4]=b2f(q.z&0xffff); xv8[5]=b2f(q.z>>16);
          xv8[6]=b2f(q.w&0xffff); xv8[7]=b2f(q.w>>16);
        }
        if(BN){
          #pragma unroll
          for(int j=0;j<8;j++){
            float2 ab = bnab[kb+koff+j];
            float y = ab.x*xv8[j]+ab.y;
            xv8[j] = y>0.f? y : __expf(y)-1.f;   // ELU
          }
        }
      } else {
        #pragma unroll
        for(int j=0;j<8;j++) xv8[j]=0.f;
      }
      #pragma unroll
      for(int j=0;j<8;j++) XT[(koff+j)*RP + sr] = xv8[j];
    }
    __syncthreads();
    if(act){
      #pragma unroll 8
      for(int kk=0;kk<KC;kk++){
        float4 xv = *(const float4*)&XT[kk*RP + r0];
        float4 wv = *(const float4*)&WS[(kb+kk)*OUTC + c0];
        acc[0][0]+=xv.x*wv.x; acc[0][1]+=xv.x*wv.y; acc[0][2]+=xv.x*wv.z; acc[0][3]+=xv.x*wv.w;
        acc[1][0]+=xv.y*wv.x; acc[1][1]+=xv.y*wv.y; acc[1][2]+=xv.y*wv.z; acc[1][3]+=xv.y*wv.w;
        acc[2][0]+=xv.z*wv.x; acc[2][1]+=xv.z*wv.y; acc[2][2]+=xv.z*wv.z; acc[2][3]+=xv.z*wv.w;
        acc[3][0]+=xv.w*wv.x; acc[3][1]+=xv.w*wv.y; acc[3][2]+=xv.w*wv.z; acc[3][3]+=xv.w*wv.w;
      }
    }
  }
  if(act){
    int head = (c0>=HIDC)?1:0;
    float av4[4], ad4[4];
    #pragma unroll
    for(int j=0;j<4;j++){ av4[j]=ldf(avs,c0+j,f); ad4[j]=ldf(avd,c0+j,f); }
    #pragma unroll
    for(int i=0;i<4;i++){
      float ps=0.f,pd=0.f;
      #pragma unroll
      for(int j=0;j<4;j++){ ps+=acc[i][j]*av4[j]; pd+=acc[i][j]*ad4[j]; }
      atomicAdd(&ared[r0+i][head],ps);
      atomicAdd(&ared[r0+i][2+head],pd);
    }
    #pragma unroll
    for(int i=0;i<4;i++){
      int grow=row0b+r0+i;
      if(grow<NNODES){
        ushort4 pk;
        pk.x=f2b(acc[i][0]); pk.y=f2b(acc[i][1]); pk.z=f2b(acc[i][2]); pk.w=f2b(acc[i][3]);
        *(ushort4*)(hout + (size_t)grow*OUTC + c0) = pk;
      }
    }
  }
  __syncthreads();
  for(int idx=t; idx<ROWS*2; idx+=256){
    int row=idx>>1, h=idx&1; int grow=row0b+row;
    if(grow<NNODES){
      asrc[grow*2+h]=ared[row][h];
      adst[grow*2+h]=ared[row][2+h];
    }
  }
}

// ---------------- fused softmax + gather-aggregate -------------------------
template<int OUTC, bool FINAL>
__global__ __launch_bounds__(256) void k_aggf(
  const int* __restrict__ row_ptr, const int* __restrict__ col,
  const u16* __restrict__ hin, const float2* __restrict__ asrc2,
  const float2* __restrict__ adst2, const void* __restrict__ bias,
  u16* __restrict__ houtb, void* __restrict__ outv, const int* __restrict__ flagp)
{
  const int f = flagp[0];
  __shared__ float vbuf[4][80];
  int wave = threadIdx.x>>6, lane=threadIdx.x&63;
  int d = blockIdx.x*4 + wave;        // NNODES % 4 == 0 -> always valid
  int base=row_ptr[d], deg=row_ptr[d+1]-base;
  int slot=lane>>3, cg=lane&7;
  float2 adv = adst2[d];
  float acc0[4]={0.f,0.f,0.f,0.f}, acc1[4]={0.f,0.f,0.f,0.f}, accx[2]={0.f,0.f};
  float s0=0.f, s1=0.f;
  for(int j=0;j<deg;j+=8){
    int jj=j+slot;
    bool valid = jj<deg;
    int cs = col[base + (valid? jj : 0)];
    if(valid){
      float2 sv = asrc2[cs];
      float e0=sv.x+adv.x; e0 = e0>0.f? e0 : NEG_SLOPE*e0; e0=fminf(e0,60.f);
      float e1=sv.y+adv.y; e1 = e1>0.f? e1 : NEG_SLOPE*e1; e1=fminf(e1,60.f);
      float p0=__expf(e0), p1=__expf(e1);
      s0+=p0; s1+=p1;
      const u16* hp = hin + (size_t)cs*OUTC;
      ushort4 ha = *(const ushort4*)(hp + cg*4);
      ushort4 hb = *(const ushort4*)(hp + 32 + cg*4);
      float pa = p0;
      float pb = FINAL ? ((cg<2)? p0 : p1) : p1;   // FINAL: ch32..39 head0
      acc0[0]+=pa*b2f(ha.x); acc0[1]+=pa*b2f(ha.y); acc0[2]+=pa*b2f(ha.z); acc0[3]+=pa*b2f(ha.w);
      acc1[0]+=pb*b2f(hb.x); acc1[1]+=pb*b2f(hb.y); acc1[2]+=pb*b2f(hb.z); acc1[3]+=pb*b2f(hb.w);
      if(FINAL){
        ushort2 hc = *(const ushort2*)(hp + 64 + cg*2);
        accx[0]+=p1*b2f(hc.x); accx[1]+=p1*b2f(hc.y);
      }
    }
  }
  #pragma unroll
  for(int o=8;o<64;o<<=1){
    s0+=__shfl_xor(s0,o,64); s1+=__shfl_xor(s1,o,64);
    #pragma unroll
    for(int k=0;k<4;k++){ acc0[k]+=__shfl_xor(acc0[k],o,64); acc1[k]+=__shfl_xor(acc1[k],o,64); }
    if(FINAL){ accx[0]+=__shfl_xor(accx[0],o,64); accx[1]+=__shfl_xor(accx[1],o,64); }
  }
  float inv0 = s0>0.f?1.f/s0:0.f, inv1 = s1>0.f?1.f/s1:0.f;
  if(!FINAL){
    if(slot==0){
      ushort4 o0,o1;
      o0.x=f2b(acc0[0]*inv0 + ldf(bias,cg*4+0,f));
      o0.y=f2b(acc0[1]*inv0 + ldf(bias,cg*4+1,f));
      o0.z=f2b(acc0[2]*inv0 + ldf(bias,cg*4+2,f));
      o0.w=f2b(acc0[3]*inv0 + ldf(bias,cg*4+3,f));
      o1.x=f2b(acc1[0]*inv1 + ldf(bias,32+cg*4+0,f));
      o1.y=f2b(acc1[1]*inv1 + ldf(bias,32+cg*4+1,f));
      o1.z=f2b(acc1[2]*inv1 + ldf(bias,32+cg*4+2,f));
      o1.w=f2b(acc1[3]*inv1 + ldf(bias,32+cg*4+3,f));
      *(ushort4*)(houtb + (size_t)d*64 + cg*4)      = o0;
      *(ushort4*)(houtb + (size_t)d*64 + 32 + cg*4) = o1;
    }
  } else {
    if(slot==0){
      #pragma unroll
      for(int k=0;k<4;k++){
        int c  = cg*4+k;
        int c2 = 32+cg*4+k;
        vbuf[wave][c]  = acc0[k]*inv0;
        vbuf[wave][c2] = acc1[k]*((c2<40)?inv0:inv1);
      }
      vbuf[wave][64+cg*2]   = accx[0]*inv1;
      vbuf[wave][64+cg*2+1] = accx[1]*inv1;
    }
    __syncthreads();
    if(lane<40){
      float res = 0.5f*(vbuf[wave][lane] + vbuf[wave][40+lane]) + ldf(bias,lane,f);
      if(f) ((float*)outv)[(size_t)d*40+lane] = res;
      else  ((__hip_bfloat16*)outv)[(size_t)d*40+lane] = __float2bfloat16(res);
    }
  }
}

// ---------------- batch norm (stats + coefficient finalize) ---------------
__global__ __launch_bounds__(256) void k_bnstats(const u16* __restrict__ h, float* __restrict__ stats){
  __shared__ float red[4][128];
  int t=threadIdx.x; int c=t&63; int g=t>>6;
  float s=0.f,q=0.f;
  for(int r=blockIdx.x*4+g; r<NNODES; r+=gridDim.x*4){
    float v=b2f(h[(size_t)r*64+c]); s+=v; q+=v*v;
  }
  red[g][c]=s; red[g][64+c]=q;
  __syncthreads();
  if(t<128){
    float tot=red[0][t]+red[1][t]+red[2][t]+red[3][t];
    atomicAdd(&stats[t], tot);
  }
}

__global__ void k_bnfinal(const float* __restrict__ stats,
                          const void* __restrict__ gm, const void* __restrict__ bt,
                          float2* __restrict__ bnab, const int* __restrict__ flagp){
  const int f = flagp[0];
  int c=threadIdx.x;
  if(c>=64) return;
  float mu=stats[c]*(1.0f/NNODES);
  float var=stats[64+c]*(1.0f/NNODES)-mu*mu;
  var = var>0.f?var:0.f;
  float A = ldf(gm,c,f)*rsqrtf(var+BN_EPS);
  float B = ldf(bt,c,f) - A*mu;
  bnab[c]=make_float2(A,B);
}

extern "C" void kernel_launch(void* const* d_in, const int* in_sizes, int n_in,
                              void* d_out, int out_size, void* d_ws, size_t ws_size,
                              hipStream_t stream){
  const void* x  =d_in[0];
  const int* ei =(const int*)d_in[1];
  const void* W0 =d_in[2];  const void* as0=d_in[3];  const void* ad0=d_in[4];
  const void* b0 =d_in[5];  const void* g0 =d_in[6];  const void* bt0=d_in[7];
  const void* W1 =d_in[8];  const void* as1=d_in[9];  const void* ad1=d_in[10];
  const void* b1 =d_in[11]; const void* g1 =d_in[12]; const void* bt1=d_in[13];
  const void* W2 =d_in[14]; const void* as2=d_in[15]; const void* ad2=d_in[16];
  const void* b2 =d_in[17];

  char* ws=(char*)d_ws;
  size_t off=0;
  auto alloc=[&](size_t bytes)->void*{ void* p=ws+off; off+=(bytes+255)&~(size_t)255; return p; };
  int*    flag   =(int*)   alloc(256);
  int*    row_ptr=(int*)   alloc((size_t)(NNODES+1)*4);
  int*    cnt    =(int*)   alloc((size_t)NNODES*4);
  int*    colx   =(int*)   alloc((size_t)ENTOT*4);
  int*    bsum   =(int*)   alloc((size_t)SCAN_NB*4);
  u16*    hA     =(u16*)   alloc((size_t)100032*80*2);
  u16*    hB0    =(u16*)   alloc((size_t)100032*64*2);
  u16*    hB1    =(u16*)   alloc((size_t)100032*64*2);
  float*  asrc   =(float*) alloc((size_t)NNODES*2*4);
  float*  adst   =(float*) alloc((size_t)NNODES*2*4);
  float*  stats  =(float*) alloc(128*4);
  float2* bnab   =(float2*)alloc(64*8);

  k_detect<<<1,256,0,stream>>>((const u16*)x, flag);

  // CSR by destination (shared by all 3 layers)
  hipMemsetAsync(cnt,0,(size_t)NNODES*4,stream);
  int gE=(ENTOT+255)/256;
  k_hist   <<<gE,256,0,stream>>>(ei,cnt);
  k_scan_a <<<SCAN_NB,256,0,stream>>>(cnt,bsum);
  k_scan_b <<<1,64,0,stream>>>(bsum);
  k_scan_c <<<SCAN_NB,256,0,stream>>>(cnt,bsum,row_ptr);
  hipMemsetAsync(cnt,0,(size_t)NNODES*4,stream);
  k_scatter2<<<SCHUNKS*NRANGE,256,0,stream>>>(ei,row_ptr,cnt,colx);

  int gN = NNODES/4;
  // ---- layer 0 ----
  k_gemm<128,64,32,64,16,16,true ,false><<<(NNODES+63)/64,256,0,stream>>>(
      x,W0,as0,ad0,nullptr,hA,asrc,adst,flag);
  k_aggf<64,false><<<gN,256,0,stream>>>(row_ptr,colx,hA,
      (const float2*)asrc,(const float2*)adst,b0,hB0,nullptr,flag);
  hipMemsetAsync(stats,0,512,stream);
  k_bnstats<<<256,256,0,stream>>>(hB0,stats);
  k_bnfinal<<<1,64,0,stream>>>(stats,g0,bt0,bnab,flag);
  // ---- layer 1 ----
  k_gemm<64,64,32,64,16,16,false,true ><<<(NNODES+63)/64,256,0,stream>>>(
      hB0,W1,as1,ad1,bnab,hA,asrc,adst,flag);
  k_aggf<64,false><<<gN,256,0,stream>>>(row_ptr,colx,hA,
      (const float2*)asrc,(const float2*)adst,b1,hB1,nullptr,flag);
  hipMemsetAsync(stats,0,512,stream);
  k_bnstats<<<256,256,0,stream>>>(hB1,stats);
  k_bnfinal<<<1,64,0,stream>>>(stats,g1,bt1,bnab,flag);
  // ---- layer 2 (head mean -> d_out) ----
  k_gemm<64,80,40,48,20,12,false,true ><<<(NNODES+47)/48,256,0,stream>>>(
      hB1,W2,as2,ad2,bnab,hA,asrc,adst,flag);
  k_aggf<80,true ><<<gN,256,0,stream>>>(row_ptr,colx,hA,
      (const float2*)asrc,(const float2*)adst,b2,nullptr,d_out,flag);

  (void)in_sizes;(void)n_in;(void)out_size;(void)ws_size;
}

// Round 6
// 599.073 us; speedup vs baseline: 1.7751x; 1.1496x over previous
//
#include <hip/hip_runtime.h>
#include <hip/hip_bf16.h>
#include <math.h>

// GAT: N=100000 nodes, E=1600000 edges (+N self loops), 3 layers.
// Inputs bf16 (runtime-detected flag kept). Intermediates bf16.
// CSR build: partition into 8 dst-range buckets (coalesced), then XCD-local scatter.
// GEMM: MFMA 16x16x32 bf16, fused BN/ELU on A-load, fused alpha-dot epilogue.

#define NNODES 100000
#define NEDGES 1600000
#define ENTOT  (NEDGES + NNODES)
#define NEG_SLOPE 0.2f
#define BN_EPS 1e-5f

#define NRANGE 8
#define RSIZE  (NNODES/NRANGE)     // 12500
#define BCAP   262144              // per-bucket capacity (mean 212.5k, sigma~430)
#define NB2    32                  // scatter blocks per range

typedef unsigned short u16;
typedef unsigned int u32;
typedef __attribute__((ext_vector_type(8))) short short8;
typedef __attribute__((ext_vector_type(4))) float f32x4;

__device__ __forceinline__ float b2f(u16 u){ union{u32 i; float f;} v; v.i=((u32)u)<<16; return v.f; }
__device__ __forceinline__ u16 f2b(float x){ __hip_bfloat16 b=__float2bfloat16(x); return *(u16*)&b; }
__device__ __forceinline__ float ldf(const void* p, int i, int f){
  return f ? ((const float*)p)[i] : b2f(((const u16*)p)[i]);
}

// ---------------- dtype probe ----------------
__global__ void k_detect(const u16* __restrict__ x, int* __restrict__ flag){
  __shared__ int bad;
  if(threadIdx.x==0) bad=0;
  __syncthreads();
  int cnt=0;
  for(int i=threadIdx.x;i<4096;i+=256){
    u16 v = x[2*i];
    int ex = (v>>7)&0xff;
    if(ex==0xff || (ex==0 && (v&0x7fff)!=0)) cnt++;
  }
  atomicAdd(&bad,cnt);
  __syncthreads();
  if(threadIdx.x==0) flag[0] = (bad>4)?1:0;   // 1 = fp32, 0 = bf16
}

// ---------------- pass A: partition edges into 8 dst-range buckets + hist ---
__global__ __launch_bounds__(256) void k_part(
    const int* __restrict__ ei, int* __restrict__ cnt,
    int* __restrict__ gptr, uint2* __restrict__ bkt){
  __shared__ uint2 buf[NRANGE][512];
  __shared__ int lcnt[NRANGE], gbase[NRANGE], fn[NRANGE];
  int t=threadIdx.x;
  if(t<NRANGE) lcnt[t]=0;
  __syncthreads();
  const int CH=(ENTOT+255)/256;
  int beg=blockIdx.x*CH, end=beg+CH; if(end>ENTOT) end=ENTOT;
  for(int i0=beg; i0<end; i0+=256){
    int i=i0+t;
    if(i<end){
      int d=(i<NEDGES)? ei[NEDGES+i] : (i-NEDGES);
      int s=(i<NEDGES)? ei[i] : d;
      atomicAdd(&cnt[d],1);
      int b=d/RSIZE;
      int p=atomicAdd(&lcnt[b],1);
      buf[b][p]=make_uint2((u32)d,(u32)s);
    }
    __syncthreads();
    if(t<NRANGE){
      int n=lcnt[t];
      if(n>=256){ gbase[t]=atomicAdd(&gptr[t],n); fn[t]=n; lcnt[t]=0; }
      else fn[t]=0;
    }
    __syncthreads();
    #pragma unroll
    for(int b=0;b<NRANGE;b++){
      int n=fn[b];
      for(int k=t;k<n;k+=256) bkt[(size_t)b*BCAP+gbase[b]+k]=buf[b][k];
    }
    __syncthreads();
  }
  if(t<NRANGE){ int n=lcnt[t]; if(n>0){ gbase[t]=atomicAdd(&gptr[t],n); fn[t]=n; } else fn[t]=0; }
  __syncthreads();
  #pragma unroll
  for(int b=0;b<NRANGE;b++){
    int n=fn[b];
    for(int k=t;k<n;k+=256) bkt[(size_t)b*BCAP+gbase[b]+k]=buf[b][k];
  }
}

// ---------------- prefix scan (row_ptr) ----------------
#define SCAN_M (NNODES+1)
#define SCAN_NB ((SCAN_M + 2047)/2048)

__global__ void k_scan_a(const int* __restrict__ cnt, int* __restrict__ bsum){
  __shared__ int red[256];
  int b=blockIdx.x, t=threadIdx.x;
  int base = b*2048 + t*8;
  int s=0;
  #pragma unroll
  for(int j=0;j<8;j++){ int idx=base+j; s += (idx<NNODES)? cnt[idx]:0; }
  red[t]=s; __syncthreads();
  for(int o=128;o>0;o>>=1){ if(t<o) red[t]+=red[t+o]; __syncthreads(); }
  if(t==0) bsum[b]=red[0];
}

__global__ void k_scan_b(int* bsum){
  if(threadIdx.x==0){
    int run=0;
    for(int i=0;i<SCAN_NB;i++){ int v=bsum[i]; bsum[i]=run; run+=v; }
  }
}

__global__ void k_scan_c(const int* __restrict__ cnt, const int* __restrict__ bsum,
                         int* __restrict__ row_ptr){
  __shared__ int lds[256];
  int b=blockIdx.x, t=threadIdx.x;
  int base=b*2048+t*8;
  int v[8]; int s=0;
  #pragma unroll
  for(int j=0;j<8;j++){ int idx=base+j; int x=(idx<NNODES)?cnt[idx]:0; v[j]=s; s+=x; }
  lds[t]=s; __syncthreads();
  for(int o=1;o<256;o<<=1){
    int other=0; if(t>=o) other=lds[t-o];
    __syncthreads();
    lds[t]+=other;
    __syncthreads();
  }
  int texcl = lds[t] - s;
  int off0 = bsum[b] + texcl;
  #pragma unroll
  for(int j=0;j<8;j++){ int idx=base+j; if(idx<SCAN_M) row_ptr[idx]=off0+v[j]; }
}

// ---------------- pass B: per-range scatter (L2-resident windows) ----------
__global__ __launch_bounds__(256) void k_scatter3(
    const uint2* __restrict__ bkt, const int* __restrict__ gptr,
    const int* __restrict__ row_ptr, int* __restrict__ nxt, int* __restrict__ col){
  int r = blockIdx.x & (NRANGE-1);
  int c = blockIdx.x >> 3;
  int n = gptr[r];
  int per = (n+NB2-1)/NB2;
  int beg = c*per, end = beg+per; if(end>n) end=n;
  const uint2* bp = bkt + (size_t)r*BCAP;
  for(int i=beg+threadIdx.x;i<end;i+=256){
    uint2 e=bp[i];
    int d=(int)e.x;
    int pos=row_ptr[d]+atomicAdd(&nxt[d],1);
    col[pos]=(int)e.y;
  }
}

// ---------------- MFMA GEMM + fused BN/ELU + alpha epilogue ----------------
// Block = 4 waves, each wave: 16 rows x OUTC cols via mfma_f32_16x16x32_bf16.
// A (x rows) loaded per-lane from global (A[m=lane&15][k=quad*8+j]);
// B = W staged transposed in LDS WT[col][K+8]; D: col=lane&15,row=quad*4+reg.
template<int K, int OUTC, int HID, bool XEXT, bool BN>
__global__ __launch_bounds__(256) void k_gemm_mfma(
    const void* __restrict__ xin, const void* __restrict__ W,
    const void* __restrict__ avs, const void* __restrict__ avd,
    const float2* __restrict__ bnab,
    u16* __restrict__ hout, float* __restrict__ asrc, float* __restrict__ adst,
    const int* __restrict__ flagp)
{
  const int f = flagp[0];
  constexpr int KP = K+8;          // WT row stride (u16), 16B-aligned rows
  constexpr int RS = OUTC+8;       // HROW row stride (u16)
  constexpr int NT = OUTC/16;      // col tiles per wave
  constexpr int KQ = K/32;         // mfma K steps
  __shared__ __align__(16) u16 WT[OUTC*KP];
  __shared__ __align__(16) u16 HROW[4*16*RS];
  __shared__ float AVb[2*OUTC];
  __shared__ float2 BB[K];
  int t=threadIdx.x;
  const u16* Wu=(const u16*)W; const float* Wf=(const float*)W;
  for(int idx=t; idx<K*OUTC; idx+=256){
    int k=idx/OUTC, c=idx-k*OUTC;
    WT[c*KP+k] = f ? f2b(Wf[idx]) : Wu[idx];
  }
  for(int idx=t; idx<2*OUTC; idx+=256)
    AVb[idx] = (idx<OUTC)? ldf(avs,idx,f) : ldf(avd,idx-OUTC,f);
  if(BN) for(int idx=t; idx<K; idx+=256) BB[idx]=bnab[idx];
  __syncthreads();

  int wv=t>>6, lane=t&63;
  int m=lane&15, quad=lane>>4;
  int grow0 = blockIdx.x*64 + wv*16;
  int growA = grow0 + m;
  bool avalid = growA < NNODES;
  int growC = avalid ? growA : 0;

  f32x4 acc[NT] = {};
  #pragma unroll
  for(int kq=0;kq<KQ;kq++){
    int k0 = kq*32 + quad*8;
    union{ u32 u[4]; short8 s8; } A;
    if(XEXT && f==1){
      const float* xr=(const float*)xin + (size_t)growC*K + k0;
      float4 p=*(const float4*)xr, q=*(const float4*)(xr+4);
      A.u[0]=f2b(p.x)|((u32)f2b(p.y)<<16);
      A.u[1]=f2b(p.z)|((u32)f2b(p.w)<<16);
      A.u[2]=f2b(q.x)|((u32)f2b(q.y)<<16);
      A.u[3]=f2b(q.z)|((u32)f2b(q.w)<<16);
    } else {
      uint4 q=*(const uint4*)((const u16*)xin + (size_t)growC*K + k0);
      A.u[0]=q.x; A.u[1]=q.y; A.u[2]=q.z; A.u[3]=q.w;
    }
    if(BN){
      #pragma unroll
      for(int j=0;j<4;j++){
        float lo=b2f(A.u[j]&0xffff), hi=b2f(A.u[j]>>16);
        float2 c1=BB[k0+2*j], c2=BB[k0+2*j+1];
        lo=c1.x*lo+c1.y; lo = lo>0.f? lo : __expf(lo)-1.f;
        hi=c2.x*hi+c2.y; hi = hi>0.f? hi : __expf(hi)-1.f;
        A.u[j]=f2b(lo)|((u32)f2b(hi)<<16);
      }
    }
    #pragma unroll
    for(int nt=0;nt<NT;nt++){
      union{ uint4 q; short8 s8; } Bf;
      Bf.q = *(const uint4*)&WT[(nt*16+m)*KP + k0];
      acc[nt] = __builtin_amdgcn_mfma_f32_16x16x32_bf16(A.s8, Bf.s8, acc[nt], 0,0,0);
    }
  }
  // write D tile to LDS (per-wave) for repack + alpha dots
  u16* hr = &HROW[wv*16*RS];
  #pragma unroll
  for(int nt=0;nt<NT;nt++){
    #pragma unroll
    for(int reg=0;reg<4;reg++)
      hr[(quad*4+reg)*RS + nt*16+m] = f2b(acc[nt][reg]);
  }
  __syncthreads();
  // alpha dots: lane -> (row=lane&15, task=lane>>4): (src,dst) x (h0,h1)
  {
    int row=lane&15, task=quad, head=task&1, sd=task>>1;
    float p=0.f;
    const u16* hrow=&hr[row*RS + head*HID];
    const float* av=&AVb[sd*OUTC + head*HID];
    #pragma unroll 8
    for(int c=0;c<HID;c++) p += b2f(hrow[c])*av[c];
    int grow=grow0+row;
    if(grow<NNODES){ (sd? adst:asrc)[grow*2+head]=p; }
  }
  // h store: uint4 (8 u16) per lane
  {
    constexpr int CH8 = OUTC/8;
    for(int idx=lane; idx<16*CH8; idx+=64){
      int rr=idx/CH8, c8=idx-rr*CH8;
      int grow=grow0+rr;
      if(grow<NNODES)
        *(uint4*)(hout + (size_t)grow*OUTC + c8*8) = *(const uint4*)&hr[rr*RS + c8*8];
    }
  }
}

// ---------------- fused softmax + gather-aggregate -------------------------
template<int OUTC, bool FINAL>
__global__ __launch_bounds__(256) void k_aggf(
  const int* __restrict__ row_ptr, const int* __restrict__ col,
  const u16* __restrict__ hin, const float2* __restrict__ asrc2,
  const float2* __restrict__ adst2, const void* __restrict__ bias,
  u16* __restrict__ houtb, void* __restrict__ outv, const int* __restrict__ flagp)
{
  const int f = flagp[0];
  __shared__ float vbuf[4][80];
  int wave = threadIdx.x>>6, lane=threadIdx.x&63;
  int d = blockIdx.x*4 + wave;        // NNODES % 4 == 0
  int base=row_ptr[d], deg=row_ptr[d+1]-base;
  int slot=lane>>3, cg=lane&7;
  float2 adv = adst2[d];
  float acc0[4]={0.f,0.f,0.f,0.f}, acc1[4]={0.f,0.f,0.f,0.f}, accx[2]={0.f,0.f};
  float s0=0.f, s1=0.f;
  for(int j=0;j<deg;j+=8){
    int jj=j+slot;
    bool valid = jj<deg;
    int cs = col[base + (valid? jj : 0)];
    if(valid){
      float2 sv = asrc2[cs];
      float e0=sv.x+adv.x; e0 = e0>0.f? e0 : NEG_SLOPE*e0; e0=fminf(e0,60.f);
      float e1=sv.y+adv.y; e1 = e1>0.f? e1 : NEG_SLOPE*e1; e1=fminf(e1,60.f);
      float p0=__expf(e0), p1=__expf(e1);
      s0+=p0; s1+=p1;
      const u16* hp = hin + (size_t)cs*OUTC;
      ushort4 ha = *(const ushort4*)(hp + cg*4);
      ushort4 hb = *(const ushort4*)(hp + 32 + cg*4);
      float pa = p0;
      float pb = FINAL ? ((cg<2)? p0 : p1) : p1;   // FINAL: ch32..39 head0
      acc0[0]+=pa*b2f(ha.x); acc0[1]+=pa*b2f(ha.y); acc0[2]+=pa*b2f(ha.z); acc0[3]+=pa*b2f(ha.w);
      acc1[0]+=pb*b2f(hb.x); acc1[1]+=pb*b2f(hb.y); acc1[2]+=pb*b2f(hb.z); acc1[3]+=pb*b2f(hb.w);
      if(FINAL){
        ushort2 hc = *(const ushort2*)(hp + 64 + cg*2);
        accx[0]+=p1*b2f(hc.x); accx[1]+=p1*b2f(hc.y);
      }
    }
  }
  #pragma unroll
  for(int o=8;o<64;o<<=1){
    s0+=__shfl_xor(s0,o,64); s1+=__shfl_xor(s1,o,64);
    #pragma unroll
    for(int k=0;k<4;k++){ acc0[k]+=__shfl_xor(acc0[k],o,64); acc1[k]+=__shfl_xor(acc1[k],o,64); }
    if(FINAL){ accx[0]+=__shfl_xor(accx[0],o,64); accx[1]+=__shfl_xor(accx[1],o,64); }
  }
  float inv0 = s0>0.f?1.f/s0:0.f, inv1 = s1>0.f?1.f/s1:0.f;
  if(!FINAL){
    if(slot==0){
      ushort4 o0,o1;
      o0.x=f2b(acc0[0]*inv0 + ldf(bias,cg*4+0,f));
      o0.y=f2b(acc0[1]*inv0 + ldf(bias,cg*4+1,f));
      o0.z=f2b(acc0[2]*inv0 + ldf(bias,cg*4+2,f));
      o0.w=f2b(acc0[3]*inv0 + ldf(bias,cg*4+3,f));
      o1.x=f2b(acc1[0]*inv1 + ldf(bias,32+cg*4+0,f));
      o1.y=f2b(acc1[1]*inv1 + ldf(bias,32+cg*4+1,f));
      o1.z=f2b(acc1[2]*inv1 + ldf(bias,32+cg*4+2,f));
      o1.w=f2b(acc1[3]*inv1 + ldf(bias,32+cg*4+3,f));
      *(ushort4*)(houtb + (size_t)d*64 + cg*4)      = o0;
      *(ushort4*)(houtb + (size_t)d*64 + 32 + cg*4) = o1;
    }
  } else {
    if(slot==0){
      #pragma unroll
      for(int k=0;k<4;k++){
        int c  = cg*4+k;
        int c2 = 32+cg*4+k;
        vbuf[wave][c]  = acc0[k]*inv0;
        vbuf[wave][c2] = acc1[k]*((c2<40)?inv0:inv1);
      }
      vbuf[wave][64+cg*2]   = accx[0]*inv1;
      vbuf[wave][64+cg*2+1] = accx[1]*inv1;
    }
    __syncthreads();
    if(lane<40){
      float res = 0.5f*(vbuf[wave][lane] + vbuf[wave][40+lane]) + ldf(bias,lane,f);
      if(f) ((float*)outv)[(size_t)d*40+lane] = res;
      else  ((__hip_bfloat16*)outv)[(size_t)d*40+lane] = __float2bfloat16(res);
    }
  }
}

// ---------------- batch norm (stats + coefficient finalize) ---------------
__global__ __launch_bounds__(256) void k_bnstats(const u16* __restrict__ h, float* __restrict__ stats){
  __shared__ float red[4][128];
  int t=threadIdx.x; int c=t&63; int g=t>>6;
  float s=0.f,q=0.f;
  for(int r=blockIdx.x*4+g; r<NNODES; r+=gridDim.x*4){
    float v=b2f(h[(size_t)r*64+c]); s+=v; q+=v*v;
  }
  red[g][c]=s; red[g][64+c]=q;
  __syncthreads();
  if(t<128){
    float tot=red[0][t]+red[1][t]+red[2][t]+red[3][t];
    atomicAdd(&stats[t], tot);
  }
}

__global__ void k_bnfinal(const float* __restrict__ stats,
                          const void* __restrict__ gm, const void* __restrict__ bt,
                          float2* __restrict__ bnab, const int* __restrict__ flagp){
  const int f = flagp[0];
  int c=threadIdx.x;
  if(c>=64) return;
  float mu=stats[c]*(1.0f/NNODES);
  float var=stats[64+c]*(1.0f/NNODES)-mu*mu;
  var = var>0.f?var:0.f;
  float A = ldf(gm,c,f)*rsqrtf(var+BN_EPS);
  float B = ldf(bt,c,f) - A*mu;
  bnab[c]=make_float2(A,B);
}

extern "C" void kernel_launch(void* const* d_in, const int* in_sizes, int n_in,
                              void* d_out, int out_size, void* d_ws, size_t ws_size,
                              hipStream_t stream){
  const void* x  =d_in[0];
  const int* ei =(const int*)d_in[1];
  const void* W0 =d_in[2];  const void* as0=d_in[3];  const void* ad0=d_in[4];
  const void* b0 =d_in[5];  const void* g0 =d_in[6];  const void* bt0=d_in[7];
  const void* W1 =d_in[8];  const void* as1=d_in[9];  const void* ad1=d_in[10];
  const void* b1 =d_in[11]; const void* g1 =d_in[12]; const void* bt1=d_in[13];
  const void* W2 =d_in[14]; const void* as2=d_in[15]; const void* ad2=d_in[16];
  const void* b2 =d_in[17];

  char* ws=(char*)d_ws;
  size_t off=0;
  auto alloc=[&](size_t bytes)->void*{ void* p=ws+off; off+=(bytes+255)&~(size_t)255; return p; };
  int*    flag   =(int*)   alloc(256);
  int*    row_ptr=(int*)   alloc((size_t)(NNODES+1)*4);
  int*    cnt    =(int*)   alloc((size_t)NNODES*4);
  int*    colx   =(int*)   alloc((size_t)ENTOT*4);
  int*    bsum   =(int*)   alloc((size_t)SCAN_NB*4);
  int*    gptr   =(int*)   alloc(256);
  uint2*  bkt    =(uint2*) alloc((size_t)NRANGE*BCAP*8);
  u16*    hA     =(u16*)   alloc((size_t)100032*80*2);
  u16*    hB0    =(u16*)   alloc((size_t)100032*64*2);
  u16*    hB1    =(u16*)   alloc((size_t)100032*64*2);
  float*  asrc   =(float*) alloc((size_t)NNODES*2*4);
  float*  adst   =(float*) alloc((size_t)NNODES*2*4);
  float*  stats  =(float*) alloc(128*4);
  float2* bnab   =(float2*)alloc(64*8);

  k_detect<<<1,256,0,stream>>>((const u16*)x, flag);

  // CSR by destination: partition -> scan -> per-range scatter
  hipMemsetAsync(cnt,0,(size_t)NNODES*4,stream);
  hipMemsetAsync(gptr,0,256,stream);
  k_part   <<<256,256,0,stream>>>(ei,cnt,gptr,bkt);
  k_scan_a <<<SCAN_NB,256,0,stream>>>(cnt,bsum);
  k_scan_b <<<1,64,0,stream>>>(bsum);
  k_scan_c <<<SCAN_NB,256,0,stream>>>(cnt,bsum,row_ptr);
  hipMemsetAsync(cnt,0,(size_t)NNODES*4,stream);
  k_scatter3<<<NRANGE*NB2,256,0,stream>>>(bkt,gptr,row_ptr,cnt,colx);

  int gG = (NNODES+63)/64;   // 1563
  int gN = NNODES/4;         // 25000
  // ---- layer 0 ----
  k_gemm_mfma<128,64,32,true ,false><<<gG,256,0,stream>>>(
      x,W0,as0,ad0,nullptr,hA,asrc,adst,flag);
  k_aggf<64,false><<<gN,256,0,stream>>>(row_ptr,colx,hA,
      (const float2*)asrc,(const float2*)adst,b0,hB0,nullptr,flag);
  hipMemsetAsync(stats,0,512,stream);
  k_bnstats<<<256,256,0,stream>>>(hB0,stats);
  k_bnfinal<<<1,64,0,stream>>>(stats,g0,bt0,bnab,flag);
  // ---- layer 1 ----
  k_gemm_mfma<64,64,32,false,true ><<<gG,256,0,stream>>>(
      hB0,W1,as1,ad1,bnab,hA,asrc,adst,flag);
  k_aggf<64,false><<<gN,256,0,stream>>>(row_ptr,colx,hA,
      (const float2*)asrc,(const float2*)adst,b1,hB1,nullptr,flag);
  hipMemsetAsync(stats,0,512,stream);
  k_bnstats<<<256,256,0,stream>>>(hB1,stats);
  k_bnfinal<<<1,64,0,stream>>>(stats,g1,bt1,bnab,flag);
  // ---- layer 2 (head mean -> d_out) ----
  k_gemm_mfma<64,80,40,false,true ><<<gG,256,0,stream>>>(
      hB1,W2,as2,ad2,bnab,hA,asrc,adst,flag);
  k_aggf<80,true ><<<gN,256,0,stream>>>(row_ptr,colx,hA,
      (const float2*)asrc,(const float2*)adst,b2,nullptr,d_out,flag);

  (void)in_sizes;(void)n_in;(void)out_size;(void)ws_size;
}